// Round 7
// baseline (1001.940 us; speedup 1.0000x reference)
//
#include <hip/hip_runtime.h>

#define NS   16384
#define NIN  16384
#define CIN  128
#define COUT 128
#define KNB  9
#define MCH  66              // 64 MLP channels + 1 (b3 ones) + 1 zero pad
#define QDIM (CIN*MCH)       // 8448, q = m*128 + j (j-fastest)
#define W0C  30.0f

typedef __bf16 bf16;
typedef bf16  bf16x8  __attribute__((ext_vector_type(8)));
typedef float floatx4 __attribute__((ext_vector_type(4)));
typedef unsigned int u32;

__device__ inline unsigned short f2bf(float f){
  u32 u = __float_as_uint(f);
  u += 0x7fffu + ((u >> 16) & 1u);   // round-to-nearest-even
  return (unsigned short)(u >> 16);
}
__device__ inline float bf2f_lo(u32 p){ return __uint_as_float(p << 16); }
__device__ inline float bf2f_hi(u32 p){ return __uint_as_float(p & 0xffff0000u); }
// pack two f32 -> two bf16 (round-half-up) in one v_perm
__device__ inline u32 packbf2(float lo, float hi){
  u32 a = __float_as_uint(lo) + 0x8000u;
  u32 b = __float_as_uint(hi) + 0x8000u;
  return __builtin_amdgcn_perm(b, a, 0x07060302u);
}

// ---------------- K0: Vt[i][q] bf16, q = m*128+j ----------------
__global__ void k0_vt(const float* __restrict__ W3, const float* __restrict__ b3,
                      unsigned short* __restrict__ Vt){
  int idx = blockIdx.x*256 + threadIdx.x;
  if (idx >= COUT*QDIM) return;
  int i = idx / QDIM;
  int q = idx - i*QDIM;
  int m = q >> 7;
  int j = q & 127;
  float v = 0.f;
  if (m < 64)       v = W3[m*16384 + i*128 + j];
  else if (m == 64) v = b3[i*128 + j];
  Vt[idx] = f2bf(v);
}

// ---------------- K1: SIREN MLP (fp32 math, bf16 out), h[pt][66] ----------------
__global__ __launch_bounds__(256) void k1_mlp(const float* __restrict__ coords,
      const float* __restrict__ W1, const float* __restrict__ b1,
      const float* __restrict__ W2, const float* __restrict__ b2,
      unsigned short* __restrict__ h){
  int lane = threadIdx.x & 63;
  int pt = blockIdx.x*4 + (threadIdx.x >> 6);
  float c0 = coords[2*pt], c1 = coords[2*pt+1];
  float z  = fmaf(c0, W1[lane], fmaf(c1, W1[64+lane], b1[lane]));
  float h1 = sinf(W0C * z);
  float acc = b2[lane];
  #pragma unroll
  for (int mp = 0; mp < 64; ++mp)
    acc = fmaf(__shfl(h1, mp, 64), W2[mp*64 + lane], acc);
  float h2 = sinf(acc);
  size_t base = (size_t)pt * MCH;
  h[base + lane] = f2bf(h2);
  if (lane == 0){ h[base+64] = 0x3F80; h[base+65] = 0; }  // 1.0, 0.0
}

// ---------------- K1tp: h[pt][66] -> hTp[g][pt] u32 (m-pair packed) ----------------
__global__ __launch_bounds__(256) void k1tp(const unsigned short* __restrict__ h,
                                            u32* __restrict__ hTp){
  __shared__ unsigned short t[128][68];
  int pt0 = blockIdx.x*128;
  int tid = threadIdx.x;
  for (int e = tid; e < 128*MCH; e += 256){
    int p = e / MCH, m = e - p*MCH;
    t[p][m] = h[(size_t)(pt0 + p)*MCH + m];
  }
  __syncthreads();
  for (int e = tid; e < 33*128; e += 256){
    int g = e >> 7, p = e & 127;
    hTp[(size_t)g*(KNB*NS) + pt0 + p] = (u32)t[p][2*g] | ((u32)t[p][2*g+1] << 16);
  }
}

// ---------------- K_tr: transpose x[b][j][p] -> xT[b][p][j] (bf16) ----------------
__global__ void k_tr(const float* __restrict__ x, unsigned short* __restrict__ xT){
  __shared__ __align__(16) float t[32][33];
  int b  = blockIdx.z;
  int j0 = blockIdx.y*32;
  int p0 = blockIdx.x*32;
  int tx = threadIdx.x, ty = threadIdx.y;
  const float*    xb  = x  + (size_t)b*CIN*NIN;
  unsigned short* xTb = xT + (size_t)b*NIN*CIN;
  #pragma unroll
  for (int n = 0; n < 4; ++n)
    t[ty+8*n][tx] = xb[(size_t)(j0+ty+8*n)*NIN + p0+tx];
  __syncthreads();
  #pragma unroll
  for (int n = 0; n < 4; ++n)
    xTb[(size_t)(p0+ty+8*n)*CIN + j0+tx] = f2bf(t[tx][ty+8*n]);
}

// ---------------- K_fused: fully wave-independent, A-frags built in registers -----
// wave = 32 l (2 tiles of 16) x 128 i (8 frags) x full q. NO LDS, NO barriers.
// lane L: rows l0+(L&15) and l0+16+(L&15); j-slice = kt*32 + (L>>4)*8.
__global__ __launch_bounds__(256, 2) void k_fused(
      const unsigned short* __restrict__ xT,   // [4][16384][128] bf16
      const u32* __restrict__ hTp,             // [33][9*16384]   u32 (m-pair)
      const int* __restrict__ nb,              // [9][16384]
      const unsigned short* __restrict__ Vt,   // [128][8448]     bf16
      const float* __restrict__ bias,
      float* __restrict__ out){
  const int tid  = threadIdx.x;
  const int lane = tid & 63;
  const int wid  = blockIdx.x*4 + (tid >> 6);   // 0..2047
  const int r0   = wid << 5;                    // 32 rows per wave
  const int b    = r0 >> 14;
  const int l0   = r0 & (NS-1);
  const int ar   = lane & 15;
  const int kl   = lane >> 4;                   // 0..3

  const char* xbB = (const char*)(xT + ((size_t)b << 21));
  const char* Vw  = (const char*)Vt + (size_t)ar*(QDIM*2) + (size_t)kl*16;

  floatx4 acc[2][8];
  #pragma unroll
  for (int tl = 0; tl < 2; ++tl)
    #pragma unroll
    for (int fi = 0; fi < 8; ++fi) acc[tl][fi] = (floatx4){0.f,0.f,0.f,0.f};

  for (int kt = 0; kt < 4; ++kt){
    // ---- gather x-hat slices for this kt (once; reused across all 33 mg) ----
    bf16x8 x0[KNB], x1[KNB];
    #pragma unroll
    for (int k = 0; k < KNB; ++k){
      int p0i = nb[k*NS + l0 + ar];
      int p1i = nb[k*NS + l0 + 16 + ar];
      x0[k] = *(const bf16x8*)(xbB + (((size_t)(u32)p0i) << 8) + kt*64 + kl*16);
      x1[k] = *(const bf16x8*)(xbB + (((size_t)(u32)p1i) << 8) + kt*64 + kl*16);
    }

    for (int mg = 0; mg < 33; ++mg){
      // h for both row-tiles (u32 = packed m-pair)
      u32 h0[KNB], h1[KNB];
      #pragma unroll
      for (int k = 0; k < KNB; ++k){
        const u32* hb = hTp + (size_t)mg*(KNB*NS) + ((size_t)k << 14) + l0;
        h0[k] = hb[ar];
        h1[k] = hb[16 + ar];
      }
      // ---- build the 4 A-fragments in registers ----
      float a00[8], a01[8], a10[8], a11[8];
      #pragma unroll
      for (int t = 0; t < 8; ++t){ a00[t]=0.f; a01[t]=0.f; a10[t]=0.f; a11[t]=0.f; }
      #pragma unroll
      for (int k = 0; k < KNB; ++k){
        float h00 = bf2f_lo(h0[k]), h01 = bf2f_hi(h0[k]);
        float h10 = bf2f_lo(h1[k]), h11 = bf2f_hi(h1[k]);
        #pragma unroll
        for (int t = 0; t < 8; ++t){
          float xf0 = (float)x0[k][t];
          float xf1 = (float)x1[k][t];
          a00[t] = fmaf(xf0, h00, a00[t]);
          a01[t] = fmaf(xf0, h01, a01[t]);
          a10[t] = fmaf(xf1, h10, a10[t]);
          a11[t] = fmaf(xf1, h11, a11[t]);
        }
      }
      union AV { u32 u[4]; bf16x8 v; } av[2][2];   // [mm][tile]
      #pragma unroll
      for (int t = 0; t < 4; ++t){
        av[0][0].u[t] = packbf2(a00[2*t], a00[2*t+1]);
        av[1][0].u[t] = packbf2(a01[2*t], a01[2*t+1]);
        av[0][1].u[t] = packbf2(a10[2*t], a10[2*t+1]);
        av[1][1].u[t] = packbf2(a11[2*t], a11[2*t+1]);
      }
      // ---- MFMA: 2 mm x 8 i-frags, bv shared across the two row-tiles ----
      #pragma unroll
      for (int mm = 0; mm < 2; ++mm){
        const char* Vq = Vw + (size_t)(mg*2 + mm)*256 + kt*64;
        #pragma unroll
        for (int fi = 0; fi < 8; ++fi){
          bf16x8 bv = *(const bf16x8*)(Vq + (size_t)fi*(16*QDIM*2));
          acc[0][fi] = __builtin_amdgcn_mfma_f32_16x16x32_bf16(av[mm][0].v, bv, acc[0][fi], 0, 0, 0);
          acc[1][fi] = __builtin_amdgcn_mfma_f32_16x16x32_bf16(av[mm][1].v, bv, acc[1][fi], 0, 0, 0);
        }
      }
    }
  }

  // ---- epilogue ----
  float* ob = out + ((size_t)b << 21);
  #pragma unroll
  for (int fi = 0; fi < 8; ++fi){
    int i = fi*16 + ar;
    float bi = bias[i];
    #pragma unroll
    for (int tl = 0; tl < 2; ++tl){
      int l = l0 + tl*16 + kl*4;
      float4 v;
      v.x = acc[tl][fi][0] + bi;
      v.y = acc[tl][fi][1] + bi;
      v.z = acc[tl][fi][2] + bi;
      v.w = acc[tl][fi][3] + bi;
      *(float4*)(ob + ((size_t)i << 14) + l) = v;
    }
  }
}

// ---------------- Naive zero-workspace fallback (correctness net) ----------------
__global__ __launch_bounds__(256) void k_naive(const float* __restrict__ x,
      const int* __restrict__ nb, const float* __restrict__ coords,
      const float* __restrict__ W1, const float* __restrict__ b1,
      const float* __restrict__ W2, const float* __restrict__ b2,
      const float* __restrict__ W3, const float* __restrict__ b3,
      const float* __restrict__ bias, float* __restrict__ out){
  __shared__ __align__(16) float hk[KNB][68];
  __shared__ int pk[KNB];
  __shared__ __align__(16) float xg[4][KNB][128];
  __shared__ __align__(16) float ul[128][66];
  int tid = threadIdx.x;
  int l = blockIdx.x;
  int lane = tid & 63, wid = tid >> 6;
  if (tid < KNB) pk[tid] = nb[tid*NS + l];
  for (int k = wid; k < KNB; k += 4){
    int pt = k*NS + l;
    float c0 = coords[2*pt], c1 = coords[2*pt+1];
    float z  = fmaf(c0, W1[lane], fmaf(c1, W1[64+lane], b1[lane]));
    float h1 = sinf(W0C*z);
    float a = b2[lane];
    for (int mp = 0; mp < 64; ++mp)
      a = fmaf(__shfl(h1, mp, 64), W2[mp*64+lane], a);
    hk[k][lane] = sinf(a);
    if (lane == 0){ hk[k][64] = 1.f; hk[k][65] = 0.f; }
  }
  __syncthreads();
  for (int idx = tid; idx < 4*KNB*128; idx += 256){
    int b = idx / (KNB*128);
    int r = idx - b*KNB*128;
    int k = r >> 7;
    int j = r & 127;
    xg[b][k][j] = x[((size_t)b*CIN + j)*NIN + pk[k]];
  }
  __syncthreads();
  for (int b = 0; b < 4; ++b){
    for (int idx = tid; idx < 128*65; idx += 256){
      int j = idx / 65, m = idx - j*65;
      float s = 0.f;
      for (int k = 0; k < KNB; ++k) s = fmaf(xg[b][k][j], hk[k][m], s);
      ul[j][m] = s;
    }
    __syncthreads();
    if (tid < 128){
      int i = tid;
      float v = bias[i];
      for (int j = 0; j < 128; ++j){
        const float* wcol = W3 + i*128 + j;
        for (int m = 0; m < 64; ++m)
          v = fmaf(ul[j][m], wcol[(size_t)m*16384], v);
        v = fmaf(ul[j][64], b3[i*128+j], v);
      }
      out[((size_t)b<<21) + ((size_t)i<<14) + l] = v;
    }
    __syncthreads();
  }
}

extern "C" void kernel_launch(void* const* d_in, const int* in_sizes, int n_in,
                              void* d_out, int out_size, void* d_ws, size_t ws_size,
                              hipStream_t stream) {
  const float* x      = (const float*)d_in[0];
  const int*   nb     = (const int*)  d_in[1];
  const float* coords = (const float*)d_in[2];
  const float* W1     = (const float*)d_in[3];
  const float* b1     = (const float*)d_in[4];
  const float* W2     = (const float*)d_in[5];
  const float* b2     = (const float*)d_in[6];
  const float* W3     = (const float*)d_in[7];
  const float* b3     = (const float*)d_in[8];
  const float* bias   = (const float*)d_in[9];
  float* out = (float*)d_out;

  const size_t VT_BYTES = (size_t)COUT*QDIM*2;            //  2,162,688
  const size_t H_BYTES  = (size_t)KNB*NS*MCH*2;           // 19,464,192
  const size_t HT_BYTES = (size_t)33*KNB*NS*4;            // 19,464,192
  const size_t XT_BYTES = (size_t)4*NIN*CIN*2;            // 16,777,216
  const size_t FIXED    = VT_BYTES + H_BYTES + HT_BYTES + XT_BYTES;  // ~57.9 MB

  if (ws_size >= FIXED) {
    char* ws = (char*)d_ws;
    unsigned short* Vt = (unsigned short*)ws;
    unsigned short* h  = (unsigned short*)(ws + VT_BYTES);
    u32*            hTp= (u32*)(ws + VT_BYTES + H_BYTES);
    unsigned short* xT = (unsigned short*)(ws + VT_BYTES + H_BYTES + HT_BYTES);

    k0_vt<<<(COUT*QDIM + 255)/256, 256, 0, stream>>>(W3, b3, Vt);
    k1_mlp<<<(KNB*NS)/4, 256, 0, stream>>>(coords, W1, b1, W2, b2, h);
    k1tp<<<(KNB*NS)/128, 256, 0, stream>>>(h, hTp);
    k_tr<<<dim3(NIN/32, CIN/32, 4), dim3(32, 8), 0, stream>>>(x, xT);
    k_fused<<<512, 256, 0, stream>>>(xT, hTp, nb, Vt, bias, out);
  } else {
    k_naive<<<NS, 256, 0, stream>>>(x, nb, coords, W1, b1, W2, b2, W3, b3, bias, out);
  }
  (void)in_sizes; (void)n_in; (void)out_size;
}